// Round 12
// baseline (833.550 us; speedup 1.0000x reference)
//
#include <hip/hip_runtime.h>

#define BATCH 4
#define NN 2048
#define MM 2048
#define DIM 128
#define HID 128

typedef __bf16 bf16x8 __attribute__((ext_vector_type(8)));
typedef float f32x16 __attribute__((ext_vector_type(16)));
typedef float f32x4 __attribute__((ext_vector_type(4)));
typedef float f32x2 __attribute__((ext_vector_type(2)));
typedef unsigned short ushort_t;
typedef ushort_t ushort8 __attribute__((ext_vector_type(8)));
typedef unsigned int uint_t;

#define LOG2E 1.44269504088896340736f
#define LN2   0.69314718055994530942f

__device__ __forceinline__ ushort_t f2bf(float f) {
  uint_t u = __builtin_bit_cast(uint_t, f);
  u += 0x7fffu + ((u >> 16) & 1u);
  return (ushort_t)(u >> 16);
}

// ---- pre-kernel: fp32 -> bf16 convert + TILE-MAJOR repack of source_val ----
// Lane-linear layout (round-6 verified): chunk t = ((b*64 + jt)*8 + ks)*64 + c
// with c == consuming LANE: half = c>>5, l5 = c&31; chunk holds
// S[b][jt*32+l5][ks*16+half*8 .. +8] as 8 bf16. Per-(jt,ks) fragment read is
// lane*16B linear -> conflict-free ds_read_b128; matches global_load_lds's
// uniform-base+lane*16 dest requirement.
__global__ void cvt_repack(const float* __restrict__ src, ushort_t* __restrict__ dst) {
  int t = blockIdx.x * 256 + threadIdx.x;   // 131072 chunks
  int c    = t & 63;
  int ks   = (t >> 6) & 7;
  int jt   = (t >> 9) & 63;
  int b    = t >> 15;
  int half = c >> 5, l5 = c & 31;           // lane-linear: c == lane
  int j    = jt * 32 + l5;
  int d0   = ks * 16 + half * 8;
  const float* s = src + ((size_t)(b * MM + j)) * DIM + d0;
  float4 v0 = *reinterpret_cast<const float4*>(s);
  float4 v1 = *reinterpret_cast<const float4*>(s + 4);
  ushort8 u;
  u[0] = f2bf(v0.x); u[1] = f2bf(v0.y); u[2] = f2bf(v0.z); u[3] = f2bf(v0.w);
  u[4] = f2bf(v1.x); u[5] = f2bf(v1.y); u[6] = f2bf(v1.z); u[7] = f2bf(v1.w);
  *reinterpret_cast<ushort8*>(dst + (size_t)t * 8) = u;
}

// ---- pre-kernel: interleaved f32 pairs (b_in*log2e, w_out*ln2) per h ----
__global__ void pbw_kernel(const float* __restrict__ b_in, const float* __restrict__ w_out,
                           float* __restrict__ pbwF) {
  int h = threadIdx.x;                    // 128
  pbwF[2 * h]     = b_in[h] * LOG2E;
  pbwF[2 * h + 1] = w_out[h] * LN2;
}

// ---------------- main kernel ----------------
// 8192 blocks = one (b,i); 4 waves; wave wv owns h-quarter [32wv,32wv+32).
// ROUND 12 — kill the r11 spill while keeping 4-block residency:
//   r11 hit 737us at (256,4) WITH ~71MB scratch (live set ~140 > 128 combined
//   VGPR+AGPR budget). Cut the last 32 loop-invariant regs:
//   * cinit (16) GONE: MFMA chain seeded with 0; bias added in epilogue.
//   * w2 (16) GONE: per pair ONE ds_read_b128 from LDS bwS fetches
//     (b0,w0,b1,w1) -- compile-time offsets, per-half broadcast (no conflict).
//   New live set ~110 <= 128. LDS 16(part)+16(Bst)+1(bwS) = 33KB -> 4 blk/CU.
//   SPILL TRIPWIRE: WRITE_SIZE must be exactly 65536 KB.
// Keeps (verified): global_load_lds staged B dbuf (lane-linear, conflict-free),
// single 8-deep MFMA chain, part[4][1024] double-flush, packed-fp32 epilogue.
__launch_bounds__(256, 4)
__global__ void hmlp_kernel(const float* __restrict__ Tg, const ushort_t* __restrict__ Sb,
                            const float* __restrict__ Wg, const float* __restrict__ pbwF,
                            const float* __restrict__ b_out_p, float* __restrict__ Og) {
  __shared__ float part[4][1024];      // 16 KB: half-row partials (flushed 2x)
  __shared__ ushort_t Bst[2][4096];    // 16 KB: double-buffered 8KB B tile
  __shared__ float bwS[256];           // 1 KB: interleaved (bias', w') per h
  const int tid  = threadIdx.x;
  const int lane = tid & 63;
  const int wv   = tid >> 6;
  const int half = lane >> 5;     // lane half (0/1)
  const int l5   = lane & 31;
  const int blk  = blockIdx.x;
  const int b    = blk >> 11;     // 2048 blocks per batch
  const int i    = blk & 2047;
  const int hb   = wv << 5;       // this wave's h-base (0/32/64/96)

  bwS[tid & 255] = pbwF[tid & 255];   // one-time copy (256 floats)

  // ---- A-fragments afr[ks] = bf16(LOG2E * t_i[d] * W[h][d]) ----
  // A row = hb + l5, k(=d) = ks*16 + half*8 + e   (verified)
  bf16x8 afr[8];
  {
    const float* tb = Tg + ((size_t)(b * NN + i)) * DIM;
    const float* wr = Wg + (size_t)(hb + l5) * DIM;
#pragma unroll
    for (int ks = 0; ks < 8; ++ks) {
      const int d0 = ks * 16 + half * 8;
      float4 w0 = *reinterpret_cast<const float4*>(wr + d0);
      float4 w1 = *reinterpret_cast<const float4*>(wr + d0 + 4);
      float4 t0 = *reinterpret_cast<const float4*>(tb + d0);
      float4 t1 = *reinterpret_cast<const float4*>(tb + d0 + 4);
      ushort8 u;
      u[0] = f2bf(w0.x * t0.x * LOG2E); u[1] = f2bf(w0.y * t0.y * LOG2E);
      u[2] = f2bf(w0.z * t0.z * LOG2E); u[3] = f2bf(w0.w * t0.w * LOG2E);
      u[4] = f2bf(w1.x * t1.x * LOG2E); u[5] = f2bf(w1.y * t1.y * LOG2E);
      u[6] = f2bf(w1.z * t1.z * LOG2E); u[7] = f2bf(w1.w * t1.w * LOG2E);
      afr[ks] = __builtin_bit_cast(bf16x8, u);
    }
  }

  // ---- B staging: async global->LDS, 16B/lane, 2 instrs per wave per jt ----
  const ushort_t* stage_base = Sb + (size_t)b * (64 * 4096);

  auto stage_async = [&](int jt, int buf) {
    const ushort_t* g0 = stage_base + (size_t)jt * 4096 + wv * 1024 + lane * 8;
    ushort_t* l0 = &Bst[buf][wv * 1024];
    __builtin_amdgcn_global_load_lds(
        (const __attribute__((address_space(1))) uint_t*)(g0),
        (__attribute__((address_space(3))) uint_t*)(l0), 16, 0, 0);
    __builtin_amdgcn_global_load_lds(
        (const __attribute__((address_space(1))) uint_t*)(g0 + 512),
        (__attribute__((address_space(3))) uint_t*)(l0 + 512), 16, 0, 0);
  };

  const float bo = b_out_p[0];
  const size_t ob = ((size_t)(b * NN + i)) * MM;
  // per-thread (bias', w') base: pair h0(q) = hb + 4*half + 2*(q&1) + 8*(q>>1)
  // float idx = 2*h0 -> base 2*(hb+4*half), offset 4*(q&1) + 16*(q>>1) floats
  // (16B-aligned: h0 even). All lanes of a half read the same addr: broadcast.
  const float* bwp = &bwS[2 * (hb + 4 * half)];

  // prologue: stage jt=0 into buf 0 (async); barrier also covers bwS copy
  stage_async(0, 0);
  __syncthreads();

#pragma unroll 1
  for (int jt = 0; jt < 64; ++jt) {
    const int buf = jt & 1;
    if (jt + 1 < 64) stage_async(jt + 1, buf ^ 1);  // async into other buffer

    // ---- compute: SINGLE 8-deep MFMA chain, zero-seeded ----
    const ushort_t* fb = &Bst[buf][lane * 8];
    f32x16 c = __builtin_amdgcn_mfma_f32_32x32x16_bf16(
        afr[0], *reinterpret_cast<const bf16x8*>(fb), (f32x16)(0.f), 0, 0, 0);
#pragma unroll
    for (int ks = 1; ks < 8; ++ks)
      c = __builtin_amdgcn_mfma_f32_32x32x16_bf16(
          afr[ks], *reinterpret_cast<const bf16x8*>(fb + ks * 512), c, 0, 0, 0);

    // epilogue (packed fp32): per pair 1 ds_read_b128 (b0,w0,b1,w1) +
    // 1 pk_add (bias) + 2 exp2 + 1 pk_add + 2 rcp + 1 pk_mul + 1 pk_fma
    f32x2 pc[4] = {f32x2{0.f, 0.f}, f32x2{0.f, 0.f}, f32x2{0.f, 0.f}, f32x2{0.f, 0.f}};
#define EPI_Q(q)                                                                     \
    {                                                                                \
      f32x4 bw4 = *reinterpret_cast<const f32x4*>(bwp + 4 * ((q) & 1) + 16 * ((q) >> 1)); \
      f32x2 y = __builtin_shufflevector(c, c, 2 * (q), 2 * (q) + 1)                  \
              + f32x2{bw4[0], bw4[2]};                                               \
      float e0 = __builtin_amdgcn_exp2f(-y.x);                                       \
      float e1 = __builtin_amdgcn_exp2f(-y.y);                                       \
      f32x2 d = f32x2{e0, e1} + 1.0f;                                                \
      f32x2 s = f32x2{__builtin_amdgcn_rcpf(d.x), __builtin_amdgcn_rcpf(d.y)};       \
      f32x2 ys = y * s;                                                              \
      pc[(q) & 3] = __builtin_elementwise_fma(f32x2{bw4[1], bw4[3]}, ys, pc[(q) & 3]); \
    }
    EPI_Q(0) EPI_Q(1) EPI_Q(2) EPI_Q(3) EPI_Q(4) EPI_Q(5) EPI_Q(6) EPI_Q(7)
#undef EPI_Q
    f32x2 pv = (pc[0] + pc[1]) + (pc[2] + pc[3]);
    float p = pv.x + pv.y;
    p += __shfl_xor(p, 32, 64);                       // combine lane-halves' h-subsets
    if (lane < 32) part[wv][(jt & 31) * 32 + l5] = p; // write-once, private row

    __syncthreads();   // buf^1 staged+ready, buf free, part writes visible

    if ((jt & 31) == 31) {
      // ---- flush half-row: sum 4 h-quarters + b_out, contiguous store ----
      const int phase = jt >> 5;                 // 0 or 1
      const int j0 = tid * 4;
      f32x4 v0 = *reinterpret_cast<const f32x4*>(&part[0][j0]);
      f32x4 v1 = *reinterpret_cast<const f32x4*>(&part[1][j0]);
      f32x4 v2 = *reinterpret_cast<const f32x4*>(&part[2][j0]);
      f32x4 v3 = *reinterpret_cast<const f32x4*>(&part[3][j0]);
      f32x4 o = (v0 + v1) + (v2 + v3);
      o[0] += bo; o[1] += bo; o[2] += bo; o[3] += bo;
      *reinterpret_cast<f32x4*>(&Og[ob + phase * 1024 + j0]) = o;
      __syncthreads();   // flush reads done before part is overwritten
    }
  }
}

// ---------------- launch ----------------
extern "C" void kernel_launch(void* const* d_in, const int* in_sizes, int n_in,
                              void* d_out, int out_size, void* d_ws, size_t ws_size,
                              hipStream_t stream) {
  const float* Tg    = (const float*)d_in[0];
  const float* Sg    = (const float*)d_in[1];
  const float* Wg    = (const float*)d_in[2];
  const float* b_in  = (const float*)d_in[3];
  const float* W_out = (const float*)d_in[4];
  const float* b_out = (const float*)d_in[5];
  float* Og = (float*)d_out;

  ushort_t* Sb = (ushort_t*)d_ws;
  float* pbwF  = (float*)((char*)d_ws + (size_t)BATCH * MM * DIM * 2);

  cvt_repack<<<(BATCH * MM * DIM) / (256 * 8), 256, 0, stream>>>(Sg, Sb);
  pbw_kernel<<<1, 128, 0, stream>>>(b_in, W_out, pbwF);
  hmlp_kernel<<<BATCH * NN, 256, 0, stream>>>(Tg, Sb, Wg, pbwF, b_out, Og);
}

// Round 13
// 799.584 us; speedup vs baseline: 1.0425x; 1.0425x over previous
//
#include <hip/hip_runtime.h>

#define BATCH 4
#define NN 2048
#define MM 2048
#define DIM 128
#define HID 128

typedef __bf16 bf16x8 __attribute__((ext_vector_type(8)));
typedef float f32x16 __attribute__((ext_vector_type(16)));
typedef float f32x4 __attribute__((ext_vector_type(4)));
typedef float f32x2 __attribute__((ext_vector_type(2)));
typedef unsigned short ushort_t;
typedef ushort_t ushort8 __attribute__((ext_vector_type(8)));
typedef unsigned int uint_t;

#define LOG2E 1.44269504088896340736f
#define LN2   0.69314718055994530942f

__device__ __forceinline__ ushort_t f2bf(float f) {
  uint_t u = __builtin_bit_cast(uint_t, f);
  u += 0x7fffu + ((u >> 16) & 1u);
  return (ushort_t)(u >> 16);
}
__device__ __forceinline__ float bflo(uint_t p) { return __builtin_bit_cast(float, p << 16); }
__device__ __forceinline__ float bfhi(uint_t p) { return __builtin_bit_cast(float, p & 0xffff0000u); }

// ---- pre-kernel: fp32 -> bf16 convert + TILE-MAJOR repack of source_val ----
// Lane-linear layout (round-6 verified): chunk t = ((b*64 + jt)*8 + ks)*64 + c
// with c == consuming LANE: half = c>>5, l5 = c&31; chunk holds
// S[b][jt*32+l5][ks*16+half*8 .. +8] as 8 bf16. Per-(jt,ks) fragment read is
// lane*16B linear -> conflict-free ds_read_b128; matches global_load_lds's
// uniform-base+lane*16 dest requirement.
__global__ void cvt_repack(const float* __restrict__ src, ushort_t* __restrict__ dst) {
  int t = blockIdx.x * 256 + threadIdx.x;   // 131072 chunks
  int c    = t & 63;
  int ks   = (t >> 6) & 7;
  int jt   = (t >> 9) & 63;
  int b    = t >> 15;
  int half = c >> 5, l5 = c & 31;           // lane-linear: c == lane
  int j    = jt * 32 + l5;
  int d0   = ks * 16 + half * 8;
  const float* s = src + ((size_t)(b * MM + j)) * DIM + d0;
  float4 v0 = *reinterpret_cast<const float4*>(s);
  float4 v1 = *reinterpret_cast<const float4*>(s + 4);
  ushort8 u;
  u[0] = f2bf(v0.x); u[1] = f2bf(v0.y); u[2] = f2bf(v0.z); u[3] = f2bf(v0.w);
  u[4] = f2bf(v1.x); u[5] = f2bf(v1.y); u[6] = f2bf(v1.z); u[7] = f2bf(v1.w);
  *reinterpret_cast<ushort8*>(dst + (size_t)t * 8) = u;
}

// ---- pre-kernel: pack (b_in*log2e, w_out*ln2) as bf16 pair per h ----
__global__ void pbw_kernel(const float* __restrict__ b_in, const float* __restrict__ w_out,
                           uint_t* __restrict__ pbw) {
  int h = threadIdx.x;
  pbw[h] = (uint_t)f2bf(b_in[h] * LOG2E) | ((uint_t)f2bf(w_out[h] * LN2) << 16);
}

// ---------------- main kernel ----------------
// 8192 blocks = one (b,i); 4 waves; wave wv owns h-quarter [32wv,32wv+32).
// ROUND 13 — batched reciprocal (r11 base, 737us proven):
//   r11/r12 A/B showed: all-register epilogue + benign ~9-reg spill (737) beats
//   no-spill + LDS-read epilogue (833). And VALUBusy(abs) in r11 = 435us ==
//   the trans-pipe model exactly (4.29e9 elem x 2 trans x 8cy / 4 SIMD / CU):
//   the kernel is TRANSCENDENTAL-PIPE bound. Cut trans count, not schedule:
//   * Montgomery batched inversion per QUAD: P=(d0 d1)(d2 d3); r=rcp(P);
//     1/d_i recovered with 2 pk_mul -- 4 exp2 + 1 rcp = 5 trans per 4 elements
//     (was 8). Trans floor 437 -> 273us. ~9 extra cheap muls/quad.
//   Numerics: d<=~700, P<=2.4e11 (f32-safe); 3 extra ~1e-7 rel roundings.
// Keeps (r11-verified): (256,4) 4-block residency, cinit bias-fold seed,
// reg w2, single 8-deep MFMA chain, gload_lds staged B dbuf (lane-linear,
// conflict-free), part[4][1024] double-flush.
__launch_bounds__(256, 4)
__global__ void hmlp_kernel(const float* __restrict__ Tg, const ushort_t* __restrict__ Sb,
                            const float* __restrict__ Wg, const uint_t* __restrict__ pbw,
                            const float* __restrict__ b_out_p, float* __restrict__ Og) {
  __shared__ float part[4][1024];      // 16 KB: half-row partials (flushed 2x)
  __shared__ ushort_t Bst[2][4096];    // 16 KB: double-buffered 8KB B tile
  const int tid  = threadIdx.x;
  const int lane = tid & 63;
  const int wv   = tid >> 6;
  const int half = lane >> 5;     // lane half (0/1)
  const int l5   = lane & 31;
  const int blk  = blockIdx.x;
  const int b    = blk >> 11;     // 2048 blocks per batch
  const int i    = blk & 2047;
  const int hb   = wv << 5;       // this wave's h-base (0/32/64/96)

  // one-time unpack: bias' -> MFMA C-in seed, w' -> packed float2 pairs
  // h_r = hb + (r&3) + 8*(r>>2) + 4*half  (C/D row map, verified)
  f32x16 cinit;
  f32x2 w2[8];
#pragma unroll
  for (int r = 0; r < 16; ++r) {
    uint_t pw = pbw[hb + (r & 3) + 8 * (r >> 2) + 4 * half];
    cinit[r] = bflo(pw);
    if (r & 1) w2[r >> 1].y = bfhi(pw); else w2[r >> 1].x = bfhi(pw);
  }

  // ---- A-fragments afr[ks] = bf16(LOG2E * t_i[d] * W[h][d]) ----
  // A row = hb + l5, k(=d) = ks*16 + half*8 + e   (verified)
  bf16x8 afr[8];
  {
    const float* tb = Tg + ((size_t)(b * NN + i)) * DIM;
    const float* wr = Wg + (size_t)(hb + l5) * DIM;
#pragma unroll
    for (int ks = 0; ks < 8; ++ks) {
      const int d0 = ks * 16 + half * 8;
      float4 w0 = *reinterpret_cast<const float4*>(wr + d0);
      float4 w1 = *reinterpret_cast<const float4*>(wr + d0 + 4);
      float4 t0 = *reinterpret_cast<const float4*>(tb + d0);
      float4 t1 = *reinterpret_cast<const float4*>(tb + d0 + 4);
      ushort8 u;
      u[0] = f2bf(w0.x * t0.x * LOG2E); u[1] = f2bf(w0.y * t0.y * LOG2E);
      u[2] = f2bf(w0.z * t0.z * LOG2E); u[3] = f2bf(w0.w * t0.w * LOG2E);
      u[4] = f2bf(w1.x * t1.x * LOG2E); u[5] = f2bf(w1.y * t1.y * LOG2E);
      u[6] = f2bf(w1.z * t1.z * LOG2E); u[7] = f2bf(w1.w * t1.w * LOG2E);
      afr[ks] = __builtin_bit_cast(bf16x8, u);
    }
  }

  // ---- B staging: async global->LDS, 16B/lane, 2 instrs per wave per jt ----
  const ushort_t* stage_base = Sb + (size_t)b * (64 * 4096);

  auto stage_async = [&](int jt, int buf) {
    const ushort_t* g0 = stage_base + (size_t)jt * 4096 + wv * 1024 + lane * 8;
    ushort_t* l0 = &Bst[buf][wv * 1024];
    __builtin_amdgcn_global_load_lds(
        (const __attribute__((address_space(1))) uint_t*)(g0),
        (__attribute__((address_space(3))) uint_t*)(l0), 16, 0, 0);
    __builtin_amdgcn_global_load_lds(
        (const __attribute__((address_space(1))) uint_t*)(g0 + 512),
        (__attribute__((address_space(3))) uint_t*)(l0 + 512), 16, 0, 0);
  };

  const float bo = b_out_p[0];
  const size_t ob = ((size_t)(b * NN + i)) * MM;

  // prologue: stage jt=0 into buf 0 (async), barrier drains it
  stage_async(0, 0);
  __syncthreads();

#pragma unroll 1
  for (int jt = 0; jt < 64; ++jt) {
    const int buf = jt & 1;
    if (jt + 1 < 64) stage_async(jt + 1, buf ^ 1);  // async into other buffer

    // ---- compute: SINGLE 8-deep MFMA chain (c seeded with bias via cinit) ----
    const ushort_t* fb = &Bst[buf][lane * 8];
    f32x16 c = __builtin_amdgcn_mfma_f32_32x32x16_bf16(
        afr[0], *reinterpret_cast<const bf16x8*>(fb), cinit, 0, 0, 0);
#pragma unroll
    for (int ks = 1; ks < 8; ++ks)
      c = __builtin_amdgcn_mfma_f32_32x32x16_bf16(
          afr[ks], *reinterpret_cast<const bf16x8*>(fb + ks * 512), c, 0, 0, 0);

    // epilogue: per QUAD (4 elements) -- 4 exp2 + ONE rcp (batched inversion)
    // s_i = 1/d_i via r=rcp(d0d1d2d3): q01=r*p23; s0=q01*d1, s1=q01*d0 (pk).
    f32x2 pc[4] = {f32x2{0.f, 0.f}, f32x2{0.f, 0.f}, f32x2{0.f, 0.f}, f32x2{0.f, 0.f}};
#define EPI_Q4(q4)                                                                   \
    {                                                                                \
      f32x2 y0 = __builtin_shufflevector(c, c, 4 * (q4), 4 * (q4) + 1);              \
      f32x2 y1 = __builtin_shufflevector(c, c, 4 * (q4) + 2, 4 * (q4) + 3);          \
      float e00 = __builtin_amdgcn_exp2f(-y0.x);                                     \
      float e01 = __builtin_amdgcn_exp2f(-y0.y);                                     \
      float e10 = __builtin_amdgcn_exp2f(-y1.x);                                     \
      float e11 = __builtin_amdgcn_exp2f(-y1.y);                                     \
      f32x2 da = f32x2{e00, e01} + 1.0f;                                             \
      f32x2 db = f32x2{e10, e11} + 1.0f;                                             \
      float p01 = da.x * da.y;                                                       \
      float p23 = db.x * db.y;                                                       \
      float rP  = __builtin_amdgcn_rcpf(p01 * p23);                                  \
      float q01 = rP * p23;                                                          \
      float q23 = rP * p01;                                                          \
      f32x2 sa = q01 * f32x2{da.y, da.x};                                            \
      f32x2 sb = q23 * f32x2{db.y, db.x};                                            \
      f32x2 ys0 = y0 * sa;                                                           \
      f32x2 ys1 = y1 * sb;                                                           \
      pc[(2 * (q4)) & 3]     = __builtin_elementwise_fma(w2[2 * (q4)],     ys0, pc[(2 * (q4)) & 3]);     \
      pc[(2 * (q4) + 1) & 3] = __builtin_elementwise_fma(w2[2 * (q4) + 1], ys1, pc[(2 * (q4) + 1) & 3]); \
    }
    EPI_Q4(0) EPI_Q4(1) EPI_Q4(2) EPI_Q4(3)
#undef EPI_Q4
    f32x2 pv = (pc[0] + pc[1]) + (pc[2] + pc[3]);
    float p = pv.x + pv.y;
    p += __shfl_xor(p, 32, 64);                       // combine lane-halves' h-subsets
    if (lane < 32) part[wv][(jt & 31) * 32 + l5] = p; // write-once, private row

    __syncthreads();   // buf^1 staged+ready, buf free, part writes visible

    if ((jt & 31) == 31) {
      // ---- flush half-row: sum 4 h-quarters + b_out, contiguous store ----
      const int phase = jt >> 5;                 // 0 or 1
      const int j0 = tid * 4;
      f32x4 v0 = *reinterpret_cast<const f32x4*>(&part[0][j0]);
      f32x4 v1 = *reinterpret_cast<const f32x4*>(&part[1][j0]);
      f32x4 v2 = *reinterpret_cast<const f32x4*>(&part[2][j0]);
      f32x4 v3 = *reinterpret_cast<const f32x4*>(&part[3][j0]);
      f32x4 o = (v0 + v1) + (v2 + v3);
      o[0] += bo; o[1] += bo; o[2] += bo; o[3] += bo;
      *reinterpret_cast<f32x4*>(&Og[ob + phase * 1024 + j0]) = o;
      __syncthreads();   // flush reads done before part is overwritten
    }
  }
}

// ---------------- launch ----------------
extern "C" void kernel_launch(void* const* d_in, const int* in_sizes, int n_in,
                              void* d_out, int out_size, void* d_ws, size_t ws_size,
                              hipStream_t stream) {
  const float* Tg    = (const float*)d_in[0];
  const float* Sg    = (const float*)d_in[1];
  const float* Wg    = (const float*)d_in[2];
  const float* b_in  = (const float*)d_in[3];
  const float* W_out = (const float*)d_in[4];
  const float* b_out = (const float*)d_in[5];
  float* Og = (float*)d_out;

  ushort_t* Sb = (ushort_t*)d_ws;
  uint_t* pbw  = (uint_t*)((char*)d_ws + (size_t)BATCH * MM * DIM * 2);

  cvt_repack<<<(BATCH * MM * DIM) / (256 * 8), 256, 0, stream>>>(Sg, Sb);
  pbw_kernel<<<1, 128, 0, stream>>>(b_in, W_out, pbw);
  hmlp_kernel<<<BATCH * NN, 256, 0, stream>>>(Tg, Sb, Wg, pbw, b_out, Og);
}

// Round 14
// 732.047 us; speedup vs baseline: 1.1387x; 1.0923x over previous
//
#include <hip/hip_runtime.h>

#define BATCH 4
#define NN 2048
#define MM 2048
#define DIM 128
#define HID 128

typedef __bf16 bf16x8 __attribute__((ext_vector_type(8)));
typedef float f32x16 __attribute__((ext_vector_type(16)));
typedef float f32x4 __attribute__((ext_vector_type(4)));
typedef float f32x2 __attribute__((ext_vector_type(2)));
typedef unsigned short ushort_t;
typedef ushort_t ushort8 __attribute__((ext_vector_type(8)));
typedef unsigned int uint_t;

#define LOG2E 1.44269504088896340736f
#define LN2   0.69314718055994530942f

__device__ __forceinline__ ushort_t f2bf(float f) {
  uint_t u = __builtin_bit_cast(uint_t, f);
  u += 0x7fffu + ((u >> 16) & 1u);
  return (ushort_t)(u >> 16);
}
__device__ __forceinline__ float bflo(uint_t p) { return __builtin_bit_cast(float, p << 16); }
__device__ __forceinline__ float bfhi(uint_t p) { return __builtin_bit_cast(float, p & 0xffff0000u); }

// ---- pre-kernel: fp32 -> bf16 convert + TILE-MAJOR repack of source_val ----
// Lane-linear layout (round-6 verified): chunk t = ((b*64 + jt)*8 + ks)*64 + c
// with c == consuming LANE: half = c>>5, l5 = c&31; chunk holds
// S[b][jt*32+l5][ks*16+half*8 .. +8] as 8 bf16. Per-(jt,ks) fragment read is
// lane*16B linear -> conflict-free ds_read_b128; matches global_load_lds's
// uniform-base+lane*16 dest requirement.
__global__ void cvt_repack(const float* __restrict__ src, ushort_t* __restrict__ dst) {
  int t = blockIdx.x * 256 + threadIdx.x;   // 131072 chunks
  int c    = t & 63;
  int ks   = (t >> 6) & 7;
  int jt   = (t >> 9) & 63;
  int b    = t >> 15;
  int half = c >> 5, l5 = c & 31;           // lane-linear: c == lane
  int j    = jt * 32 + l5;
  int d0   = ks * 16 + half * 8;
  const float* s = src + ((size_t)(b * MM + j)) * DIM + d0;
  float4 v0 = *reinterpret_cast<const float4*>(s);
  float4 v1 = *reinterpret_cast<const float4*>(s + 4);
  ushort8 u;
  u[0] = f2bf(v0.x); u[1] = f2bf(v0.y); u[2] = f2bf(v0.z); u[3] = f2bf(v0.w);
  u[4] = f2bf(v1.x); u[5] = f2bf(v1.y); u[6] = f2bf(v1.z); u[7] = f2bf(v1.w);
  *reinterpret_cast<ushort8*>(dst + (size_t)t * 8) = u;
}

// ---- pre-kernel: pack (b_in*log2e, w_out*ln2) as bf16 pair per h ----
__global__ void pbw_kernel(const float* __restrict__ b_in, const float* __restrict__ w_out,
                           uint_t* __restrict__ pbw) {
  int h = threadIdx.x;
  pbw[h] = (uint_t)f2bf(b_in[h] * LOG2E) | ((uint_t)f2bf(w_out[h] * LN2) << 16);
}

// ---------------- main kernel ----------------
// 8192 blocks = one (b,i); 4 waves; wave wv owns h-quarter [32wv,32wv+32).
// ROUND 14 — r11 (737us best) + 12-register diet to kill the in-loop spill:
//   r12 (LDS epilogue reads) and r13 (batched rcp) both LOST to r11's simple
//   all-register epilogue -> it is locally optimal. r11's one defect: ~71MB
//   of per-jt scratch stores (live ~140 > 128 combined budget at 4 waves/EU).
//   Diet, NO new LDS traffic in the loop:
//   * w' stored as bf16 PAIRS in 8 uints (was 16 f32 regs); per-pair unpack
//     = 1 lshl + 1 and (bit-identical w' bf16 values -> numerics unchanged).
//   * pc[4] -> pc[2] accumulator chains (ILP 2 suffices at 4 waves/SIMD).
//   Live set ~140-12 = ~128. SPILL TRIPWIRE: WRITE_SIZE == 65536 KB exactly;
//   if still inflated, r11 is the plateau.
// Keeps (r11-verified): (256,4), cinit bias-fold seed, single 8-deep MFMA
// chain, gload_lds staged B dbuf (lane-linear, conflict-free), per-jt barrier,
// part[4][1024] double-flush, packed-fp32 epilogue.
__launch_bounds__(256, 4)
__global__ void hmlp_kernel(const float* __restrict__ Tg, const ushort_t* __restrict__ Sb,
                            const float* __restrict__ Wg, const uint_t* __restrict__ pbw,
                            const float* __restrict__ b_out_p, float* __restrict__ Og) {
  __shared__ float part[4][1024];      // 16 KB: half-row partials (flushed 2x)
  __shared__ ushort_t Bst[2][4096];    // 16 KB: double-buffered 8KB B tile
  const int tid  = threadIdx.x;
  const int lane = tid & 63;
  const int wv   = tid >> 6;
  const int half = lane >> 5;     // lane half (0/1)
  const int l5   = lane & 31;
  const int blk  = blockIdx.x;
  const int b    = blk >> 11;     // 2048 blocks per batch
  const int i    = blk & 2047;
  const int hb   = wv << 5;       // this wave's h-base (0/32/64/96)

  // one-time unpack: bias' -> MFMA C-in seed (16 regs); w' -> bf16 pairs in
  // 8 uints: wp[q] = w'(h(2q)) in low16 | w'(h(2q+1)) in high16.
  // h_r = hb + (r&3) + 8*(r>>2) + 4*half  (C/D row map, verified)
  f32x16 cinit;
  uint_t wp[8];
#pragma unroll
  for (int r = 0; r < 16; ++r) {
    uint_t pw = pbw[hb + (r & 3) + 8 * (r >> 2) + 4 * half];
    cinit[r] = bflo(pw);
    if (r & 1) wp[r >> 1] |= (pw & 0xffff0000u);
    else       wp[r >> 1]  = (pw >> 16);
  }

  // ---- A-fragments afr[ks] = bf16(LOG2E * t_i[d] * W[h][d]) ----
  // A row = hb + l5, k(=d) = ks*16 + half*8 + e   (verified)
  bf16x8 afr[8];
  {
    const float* tb = Tg + ((size_t)(b * NN + i)) * DIM;
    const float* wr = Wg + (size_t)(hb + l5) * DIM;
#pragma unroll
    for (int ks = 0; ks < 8; ++ks) {
      const int d0 = ks * 16 + half * 8;
      float4 w0 = *reinterpret_cast<const float4*>(wr + d0);
      float4 w1 = *reinterpret_cast<const float4*>(wr + d0 + 4);
      float4 t0 = *reinterpret_cast<const float4*>(tb + d0);
      float4 t1 = *reinterpret_cast<const float4*>(tb + d0 + 4);
      ushort8 u;
      u[0] = f2bf(w0.x * t0.x * LOG2E); u[1] = f2bf(w0.y * t0.y * LOG2E);
      u[2] = f2bf(w0.z * t0.z * LOG2E); u[3] = f2bf(w0.w * t0.w * LOG2E);
      u[4] = f2bf(w1.x * t1.x * LOG2E); u[5] = f2bf(w1.y * t1.y * LOG2E);
      u[6] = f2bf(w1.z * t1.z * LOG2E); u[7] = f2bf(w1.w * t1.w * LOG2E);
      afr[ks] = __builtin_bit_cast(bf16x8, u);
    }
  }

  // ---- B staging: async global->LDS, 16B/lane, 2 instrs per wave per jt ----
  const ushort_t* stage_base = Sb + (size_t)b * (64 * 4096);

  auto stage_async = [&](int jt, int buf) {
    const ushort_t* g0 = stage_base + (size_t)jt * 4096 + wv * 1024 + lane * 8;
    ushort_t* l0 = &Bst[buf][wv * 1024];
    __builtin_amdgcn_global_load_lds(
        (const __attribute__((address_space(1))) uint_t*)(g0),
        (__attribute__((address_space(3))) uint_t*)(l0), 16, 0, 0);
    __builtin_amdgcn_global_load_lds(
        (const __attribute__((address_space(1))) uint_t*)(g0 + 512),
        (__attribute__((address_space(3))) uint_t*)(l0 + 512), 16, 0, 0);
  };

  const float bo = b_out_p[0];
  const size_t ob = ((size_t)(b * NN + i)) * MM;

  // prologue: stage jt=0 into buf 0 (async), barrier drains it
  stage_async(0, 0);
  __syncthreads();

#pragma unroll 1
  for (int jt = 0; jt < 64; ++jt) {
    const int buf = jt & 1;
    if (jt + 1 < 64) stage_async(jt + 1, buf ^ 1);  // async into other buffer

    // ---- compute: SINGLE 8-deep MFMA chain (c seeded with bias via cinit) ----
    const ushort_t* fb = &Bst[buf][lane * 8];
    f32x16 c = __builtin_amdgcn_mfma_f32_32x32x16_bf16(
        afr[0], *reinterpret_cast<const bf16x8*>(fb), cinit, 0, 0, 0);
#pragma unroll
    for (int ks = 1; ks < 8; ++ks)
      c = __builtin_amdgcn_mfma_f32_32x32x16_bf16(
          afr[ks], *reinterpret_cast<const bf16x8*>(fb + ks * 512), c, 0, 0, 0);

    // epilogue (packed fp32, r11 form): per pair 2 exp2 + 1 pk_add + 2 rcp +
    // 1 pk_mul + 1 pk_fma (+1 lshl +1 and for the w' unpack)
    f32x2 pc[2] = {f32x2{0.f, 0.f}, f32x2{0.f, 0.f}};
#define EPI_Q(q)                                                                     \
    {                                                                                \
      f32x2 y = __builtin_shufflevector(c, c, 2 * (q), 2 * (q) + 1);                 \
      float e0 = __builtin_amdgcn_exp2f(-y.x);                                       \
      float e1 = __builtin_amdgcn_exp2f(-y.y);                                       \
      f32x2 d = f32x2{e0, e1} + 1.0f;                                                \
      f32x2 s = f32x2{__builtin_amdgcn_rcpf(d.x), __builtin_amdgcn_rcpf(d.y)};       \
      f32x2 ys = y * s;                                                              \
      f32x2 wq = f32x2{bflo(wp[(q)]), bfhi(wp[(q)])};                                \
      pc[(q) & 1] = __builtin_elementwise_fma(wq, ys, pc[(q) & 1]);                  \
    }
    EPI_Q(0) EPI_Q(1) EPI_Q(2) EPI_Q(3) EPI_Q(4) EPI_Q(5) EPI_Q(6) EPI_Q(7)
#undef EPI_Q
    f32x2 pv = pc[0] + pc[1];
    float p = pv.x + pv.y;
    p += __shfl_xor(p, 32, 64);                       // combine lane-halves' h-subsets
    if (lane < 32) part[wv][(jt & 31) * 32 + l5] = p; // write-once, private row

    __syncthreads();   // buf^1 staged+ready, buf free, part writes visible

    if ((jt & 31) == 31) {
      // ---- flush half-row: sum 4 h-quarters + b_out, contiguous store ----
      const int phase = jt >> 5;                 // 0 or 1
      const int j0 = tid * 4;
      f32x4 v0 = *reinterpret_cast<const f32x4*>(&part[0][j0]);
      f32x4 v1 = *reinterpret_cast<const f32x4*>(&part[1][j0]);
      f32x4 v2 = *reinterpret_cast<const f32x4*>(&part[2][j0]);
      f32x4 v3 = *reinterpret_cast<const f32x4*>(&part[3][j0]);
      f32x4 o = (v0 + v1) + (v2 + v3);
      o[0] += bo; o[1] += bo; o[2] += bo; o[3] += bo;
      *reinterpret_cast<f32x4*>(&Og[ob + phase * 1024 + j0]) = o;
      __syncthreads();   // flush reads done before part is overwritten
    }
  }
}

// ---------------- launch ----------------
extern "C" void kernel_launch(void* const* d_in, const int* in_sizes, int n_in,
                              void* d_out, int out_size, void* d_ws, size_t ws_size,
                              hipStream_t stream) {
  const float* Tg    = (const float*)d_in[0];
  const float* Sg    = (const float*)d_in[1];
  const float* Wg    = (const float*)d_in[2];
  const float* b_in  = (const float*)d_in[3];
  const float* W_out = (const float*)d_in[4];
  const float* b_out = (const float*)d_in[5];
  float* Og = (float*)d_out;

  ushort_t* Sb = (ushort_t*)d_ws;
  uint_t* pbw  = (uint_t*)((char*)d_ws + (size_t)BATCH * MM * DIM * 2);

  cvt_repack<<<(BATCH * MM * DIM) / (256 * 8), 256, 0, stream>>>(Sg, Sb);
  pbw_kernel<<<1, 128, 0, stream>>>(b_in, W_out, pbw);
  hmlp_kernel<<<BATCH * NN, 256, 0, stream>>>(Tg, Sb, Wg, pbw, b_out, Og);
}

// Round 15
// 730.464 us; speedup vs baseline: 1.1411x; 1.0022x over previous
//
#include <hip/hip_runtime.h>

#define BATCH 4
#define NN 2048
#define MM 2048
#define DIM 128
#define HID 128

typedef __bf16 bf16x8 __attribute__((ext_vector_type(8)));
typedef float f32x16 __attribute__((ext_vector_type(16)));
typedef float f32x4 __attribute__((ext_vector_type(4)));
typedef float f32x2 __attribute__((ext_vector_type(2)));
typedef unsigned short ushort_t;
typedef ushort_t ushort8 __attribute__((ext_vector_type(8)));
typedef unsigned int uint_t;

#define LOG2E 1.44269504088896340736f
#define LN2   0.69314718055994530942f

__device__ __forceinline__ ushort_t f2bf(float f) {
  uint_t u = __builtin_bit_cast(uint_t, f);
  u += 0x7fffu + ((u >> 16) & 1u);
  return (ushort_t)(u >> 16);
}
__device__ __forceinline__ float bflo(uint_t p) { return __builtin_bit_cast(float, p << 16); }
__device__ __forceinline__ float bfhi(uint_t p) { return __builtin_bit_cast(float, p & 0xffff0000u); }

// ---- pre-kernel: fp32 -> bf16 convert + TILE-MAJOR repack of source_val ----
// Lane-linear layout (round-6 verified): chunk t = ((b*64 + jt)*8 + ks)*64 + c
// with c == consuming LANE: half = c>>5, l5 = c&31; chunk holds
// S[b][jt*32+l5][ks*16+half*8 .. +8] as 8 bf16. Per-(jt,ks) fragment read is
// lane*16B linear -> conflict-free ds_read_b128; matches global_load_lds's
// uniform-base+lane*16 dest requirement.
__global__ void cvt_repack(const float* __restrict__ src, ushort_t* __restrict__ dst) {
  int t = blockIdx.x * 256 + threadIdx.x;   // 131072 chunks
  int c    = t & 63;
  int ks   = (t >> 6) & 7;
  int jt   = (t >> 9) & 63;
  int b    = t >> 15;
  int half = c >> 5, l5 = c & 31;           // lane-linear: c == lane
  int j    = jt * 32 + l5;
  int d0   = ks * 16 + half * 8;
  const float* s = src + ((size_t)(b * MM + j)) * DIM + d0;
  float4 v0 = *reinterpret_cast<const float4*>(s);
  float4 v1 = *reinterpret_cast<const float4*>(s + 4);
  ushort8 u;
  u[0] = f2bf(v0.x); u[1] = f2bf(v0.y); u[2] = f2bf(v0.z); u[3] = f2bf(v0.w);
  u[4] = f2bf(v1.x); u[5] = f2bf(v1.y); u[6] = f2bf(v1.z); u[7] = f2bf(v1.w);
  *reinterpret_cast<ushort8*>(dst + (size_t)t * 8) = u;
}

// ---- pre-kernel: pack (b_in*log2e, w_out*ln2) as bf16 pair per h ----
__global__ void pbw_kernel(const float* __restrict__ b_in, const float* __restrict__ w_out,
                           uint_t* __restrict__ pbw) {
  int h = threadIdx.x;
  pbw[h] = (uint_t)f2bf(b_in[h] * LOG2E) | ((uint_t)f2bf(w_out[h] * LN2) << 16);
}

// ---------------- main kernel ----------------
// 8192 blocks = one (b,i); 4 waves; wave wv owns h-quarter [32wv,32wv+32).
// ROUND 15 — deferred-epilogue software pipeline (T15-style):
//   r14 analysis: trans floor 218us + regular VALU ~95us vs dur 732 at
//   VALUBusy 59% -> ~40% issue-idle. Cause: strict per-jt sequence
//   ds_read->MFMA(lgkm latency)->trans burst->barrier; pipes idle in turn.
//   Fix: carry the accumulator ONE iteration (cA/cB, unroll x2, named regs --
//   no dynamic indexing): MFMA(jt) interleaves with epilogue(jt-1) in the
//   same scheduling region (independent streams -> compiler co-schedules
//   trans into the MFMA/lgkm shadow).
//   Register room for the 2nd acc: cinit (16) dropped; chains seed 0, bias
//   added in epilogue from packed bf16 bp[8] (mirror of r14's wp; +3 cheap
//   ops/pair). TRIPWIRE: WRITE > 200MB = accumulator spilled -> revert r14.
// Keeps (verified): (256,4) 4-block residency, single 8-deep MFMA chain/acc,
// gload_lds staged B dbuf (lane-linear, conflict-free), part[4][1024]
// double-flush, packed-fp32 epilogue (r11 form), wp bf16-pair packing.
__launch_bounds__(256, 4)
__global__ void hmlp_kernel(const float* __restrict__ Tg, const ushort_t* __restrict__ Sb,
                            const float* __restrict__ Wg, const uint_t* __restrict__ pbw,
                            const float* __restrict__ b_out_p, float* __restrict__ Og) {
  __shared__ float part[4][1024];      // 16 KB: half-row partials (flushed 2x)
  __shared__ ushort_t Bst[2][4096];    // 16 KB: double-buffered 8KB B tile
  const int tid  = threadIdx.x;
  const int lane = tid & 63;
  const int wv   = tid >> 6;
  const int half = lane >> 5;     // lane half (0/1)
  const int l5   = lane & 31;
  const int blk  = blockIdx.x;
  const int b    = blk >> 11;     // 2048 blocks per batch
  const int i    = blk & 2047;
  const int hb   = wv << 5;       // this wave's h-base (0/32/64/96)

  // one-time unpack: bias' and w' as bf16 PAIRS in 8+8 uints.
  // h_r = hb + (r&3) + 8*(r>>2) + 4*half  (C/D row map, verified)
  uint_t bp[8], wp[8];
#pragma unroll
  for (int r = 0; r < 16; ++r) {
    uint_t pw = pbw[hb + (r & 3) + 8 * (r >> 2) + 4 * half];
    if (r & 1) { bp[r >> 1] |= (pw << 16);       wp[r >> 1] |= (pw & 0xffff0000u); }
    else       { bp[r >> 1]  = (pw & 0xffffu);   wp[r >> 1]  = (pw >> 16); }
  }

  // ---- A-fragments afr[ks] = bf16(LOG2E * t_i[d] * W[h][d]) ----
  // A row = hb + l5, k(=d) = ks*16 + half*8 + e   (verified)
  bf16x8 afr[8];
  {
    const float* tb = Tg + ((size_t)(b * NN + i)) * DIM;
    const float* wr = Wg + (size_t)(hb + l5) * DIM;
#pragma unroll
    for (int ks = 0; ks < 8; ++ks) {
      const int d0 = ks * 16 + half * 8;
      float4 w0 = *reinterpret_cast<const float4*>(wr + d0);
      float4 w1 = *reinterpret_cast<const float4*>(wr + d0 + 4);
      float4 t0 = *reinterpret_cast<const float4*>(tb + d0);
      float4 t1 = *reinterpret_cast<const float4*>(tb + d0 + 4);
      ushort8 u;
      u[0] = f2bf(w0.x * t0.x * LOG2E); u[1] = f2bf(w0.y * t0.y * LOG2E);
      u[2] = f2bf(w0.z * t0.z * LOG2E); u[3] = f2bf(w0.w * t0.w * LOG2E);
      u[4] = f2bf(w1.x * t1.x * LOG2E); u[5] = f2bf(w1.y * t1.y * LOG2E);
      u[6] = f2bf(w1.z * t1.z * LOG2E); u[7] = f2bf(w1.w * t1.w * LOG2E);
      afr[ks] = __builtin_bit_cast(bf16x8, u);
    }
  }

  // ---- B staging: async global->LDS, 16B/lane, 2 instrs per wave per jt ----
  const ushort_t* stage_base = Sb + (size_t)b * (64 * 4096);

  auto stage_async = [&](int jt, int buf) {
    const ushort_t* g0 = stage_base + (size_t)jt * 4096 + wv * 1024 + lane * 8;
    ushort_t* l0 = &Bst[buf][wv * 1024];
    __builtin_amdgcn_global_load_lds(
        (const __attribute__((address_space(1))) uint_t*)(g0),
        (__attribute__((address_space(3))) uint_t*)(l0), 16, 0, 0);
    __builtin_amdgcn_global_load_lds(
        (const __attribute__((address_space(1))) uint_t*)(g0 + 512),
        (__attribute__((address_space(3))) uint_t*)(l0 + 512), 16, 0, 0);
  };

  // single 8-deep MFMA chain from LDS buffer `buf`, zero-seeded
  auto chain = [&](int buf) -> f32x16 {
    const ushort_t* fb = &Bst[buf][lane * 8];
    f32x16 c = __builtin_amdgcn_mfma_f32_32x32x16_bf16(
        afr[0], *reinterpret_cast<const bf16x8*>(fb), (f32x16)(0.f), 0, 0, 0);
#pragma unroll
    for (int ks = 1; ks < 8; ++ks)
      c = __builtin_amdgcn_mfma_f32_32x32x16_bf16(
          afr[ks], *reinterpret_cast<const bf16x8*>(fb + ks * 512), c, 0, 0, 0);
    return c;
  };

  // epilogue for accumulator `c` belonging to j-tile `jtv`
  auto epi = [&](const f32x16& c, int jtv) {
    f32x2 pc[2] = {f32x2{0.f, 0.f}, f32x2{0.f, 0.f}};
#define EPI_Q(q)                                                                     \
    {                                                                                \
      f32x2 y = __builtin_shufflevector(c, c, 2 * (q), 2 * (q) + 1)                  \
              + f32x2{bflo(bp[(q)]), bfhi(bp[(q)])};                                 \
      float e0 = __builtin_amdgcn_exp2f(-y.x);                                       \
      float e1 = __builtin_amdgcn_exp2f(-y.y);                                       \
      f32x2 d = f32x2{e0, e1} + 1.0f;                                                \
      f32x2 s = f32x2{__builtin_amdgcn_rcpf(d.x), __builtin_amdgcn_rcpf(d.y)};       \
      f32x2 ys = y * s;                                                              \
      f32x2 wq = f32x2{bflo(wp[(q)]), bfhi(wp[(q)])};                                \
      pc[(q) & 1] = __builtin_elementwise_fma(wq, ys, pc[(q) & 1]);                  \
    }
    EPI_Q(0) EPI_Q(1) EPI_Q(2) EPI_Q(3) EPI_Q(4) EPI_Q(5) EPI_Q(6) EPI_Q(7)
#undef EPI_Q
    f32x2 pv = pc[0] + pc[1];
    float p = pv.x + pv.y;
    p += __shfl_xor(p, 32, 64);                        // combine lane-halves' h-subsets
    if (lane < 32) part[wv][(jtv & 31) * 32 + l5] = p; // write-once, private row
  };

  const float bo = b_out_p[0];
  const size_t ob = ((size_t)(b * NN + i)) * MM;

  auto flush = [&](int phase) {
    const int j0 = tid * 4;
    f32x4 v0 = *reinterpret_cast<const f32x4*>(&part[0][j0]);
    f32x4 v1 = *reinterpret_cast<const f32x4*>(&part[1][j0]);
    f32x4 v2 = *reinterpret_cast<const f32x4*>(&part[2][j0]);
    f32x4 v3 = *reinterpret_cast<const f32x4*>(&part[3][j0]);
    f32x4 o = (v0 + v1) + (v2 + v3);
    o[0] += bo; o[1] += bo; o[2] += bo; o[3] += bo;
    *reinterpret_cast<f32x4*>(&Og[ob + phase * 1024 + j0]) = o;
  };

  // ---- prologue: stage jt=0 and jt=1; compute cA = chain(jt=0) ----
  stage_async(0, 0);
  __syncthreads();                 // jt0 staged
  stage_async(1, 1);
  f32x16 cA = chain(0);            // jt = 0
  f32x16 cB;
  __syncthreads();                 // jt1 staged; all reads of Bst[0] done

  // ---- pipelined loop: MFMA(jt) || epilogue(jt-1), unrolled x2 ----
#pragma unroll 1
  for (int jt = 1; jt < 63; jt += 2) {
    // iter A: jt (odd, buf 1); epilogue for jt-1 (cA)
    stage_async(jt + 1, 0);
    cB = chain(1);
    epi(cA, jt - 1);               // (jt-1)&31 never 31 here (even)
    __syncthreads();               // stage(jt+1) landed; Bst[1] reads done

    // iter B: jt+1 (even, buf 0); epilogue for jt (cB)
    if (jt + 2 < 64) stage_async(jt + 2, 1);
    cA = chain(0);
    epi(cB, jt);
    __syncthreads();               // stage(jt+2) landed; Bst[0] reads done
    if ((jt & 31) == 31) {         // jt==31: phase-0 rows complete
      flush(0);
      __syncthreads();             // flush reads done before rows reused
    }
  }

  // ---- tail: jt=63 (buf 1, staged at jt=61 iterB) ----
  cB = chain(1);
  epi(cA, 62);
  epi(cB, 63);
  __syncthreads();                 // all phase-1 rows written
  flush(1);
}

// ---------------- launch ----------------
extern "C" void kernel_launch(void* const* d_in, const int* in_sizes, int n_in,
                              void* d_out, int out_size, void* d_ws, size_t ws_size,
                              hipStream_t stream) {
  const float* Tg    = (const float*)d_in[0];
  const float* Sg    = (const float*)d_in[1];
  const float* Wg    = (const float*)d_in[2];
  const float* b_in  = (const float*)d_in[3];
  const float* W_out = (const float*)d_in[4];
  const float* b_out = (const float*)d_in[5];
  float* Og = (float*)d_out;

  ushort_t* Sb = (ushort_t*)d_ws;
  uint_t* pbw  = (uint_t*)((char*)d_ws + (size_t)BATCH * MM * DIM * 2);

  cvt_repack<<<(BATCH * MM * DIM) / (256 * 8), 256, 0, stream>>>(Sg, Sb);
  pbw_kernel<<<1, 128, 0, stream>>>(b_in, W_out, pbw);
  hmlp_kernel<<<BATCH * NN, 256, 0, stream>>>(Tg, Sb, Wg, pbw, b_out, Og);
}

// Round 16
// 699.856 us; speedup vs baseline: 1.1910x; 1.0437x over previous
//
#include <hip/hip_runtime.h>

#define BATCH 4
#define NN 2048
#define MM 2048
#define DIM 128
#define HID 128

typedef __bf16 bf16x8 __attribute__((ext_vector_type(8)));
typedef float f32x16 __attribute__((ext_vector_type(16)));
typedef float f32x4 __attribute__((ext_vector_type(4)));
typedef float f32x2 __attribute__((ext_vector_type(2)));
typedef unsigned short ushort_t;
typedef ushort_t ushort8 __attribute__((ext_vector_type(8)));
typedef unsigned int uint_t;

#define LOG2E 1.44269504088896340736f
#define LN2   0.69314718055994530942f

__device__ __forceinline__ ushort_t f2bf(float f) {
  uint_t u = __builtin_bit_cast(uint_t, f);
  u += 0x7fffu + ((u >> 16) & 1u);
  return (ushort_t)(u >> 16);
}
__device__ __forceinline__ float bflo(uint_t p) { return __builtin_bit_cast(float, p << 16); }
__device__ __forceinline__ float bfhi(uint_t p) { return __builtin_bit_cast(float, p & 0xffff0000u); }

// ---- pre-kernel: fp32 -> bf16 convert + TILE-MAJOR repack of source_val ----
// Lane-linear layout (round-6 verified): chunk t = ((b*64 + jt)*8 + ks)*64 + c
// with c == consuming LANE: half = c>>5, l5 = c&31; chunk holds
// S[b][jt*32+l5][ks*16+half*8 .. +8] as 8 bf16. Per-(jt,ks) fragment read is
// lane*16B linear -> conflict-free ds_read_b128; matches global_load_lds's
// uniform-base+lane*16 dest requirement.
__global__ void cvt_repack(const float* __restrict__ src, ushort_t* __restrict__ dst) {
  int t = blockIdx.x * 256 + threadIdx.x;   // 131072 chunks
  int c    = t & 63;
  int ks   = (t >> 6) & 7;
  int jt   = (t >> 9) & 63;
  int b    = t >> 15;
  int half = c >> 5, l5 = c & 31;           // lane-linear: c == lane
  int j    = jt * 32 + l5;
  int d0   = ks * 16 + half * 8;
  const float* s = src + ((size_t)(b * MM + j)) * DIM + d0;
  float4 v0 = *reinterpret_cast<const float4*>(s);
  float4 v1 = *reinterpret_cast<const float4*>(s + 4);
  ushort8 u;
  u[0] = f2bf(v0.x); u[1] = f2bf(v0.y); u[2] = f2bf(v0.z); u[3] = f2bf(v0.w);
  u[4] = f2bf(v1.x); u[5] = f2bf(v1.y); u[6] = f2bf(v1.z); u[7] = f2bf(v1.w);
  *reinterpret_cast<ushort8*>(dst + (size_t)t * 8) = u;
}

// ---- pre-kernel: pack (b_in*log2e, w_out*ln2) as bf16 pair per h ----
__global__ void pbw_kernel(const float* __restrict__ b_in, const float* __restrict__ w_out,
                           uint_t* __restrict__ pbw) {
  int h = threadIdx.x;
  pbw[h] = (uint_t)f2bf(b_in[h] * LOG2E) | ((uint_t)f2bf(w_out[h] * LN2) << 16);
}

// ---------------- main kernel ----------------
// 8192 blocks = one (b,i); 4 waves; wave wv owns h-quarter [32wv,32wv+32).
// ROUND 16 — r15 pipeline + lean epilogue (buy back cinit/w2):
//   r15 killed the spill (WRITE == 65536 exactly) and raised VALUBusy to 68%,
//   but its epilogue carries 5 extra slots/pair that only existed to free
//   registers: bias pk_add + 4 bit-unpacks. With the spill gone there is
//   budget to restore them as registers:
//   * cinit (16 regs) back: BOTH accumulator chains seed with it (each jt's
//     acc gets bias exactly once -- r11-verified formulation).
//   * w2[8] f32 pairs (16 regs) back: no per-pair unpack.
//   Epilogue: 12 -> 7 slots/pair (4 trans + 3 pk). Live set ~120-130 vs 128.
//   TRIPWIRE: WRITE must stay 65536 KB; if ballooned, r15 is the fallback.
// Keeps (verified): deferred-epilogue pipeline (cA/cB, unroll x2, named regs),
// (256,4) 4-block residency, single 8-deep MFMA chain per acc, gload_lds
// staged B dbuf (lane-linear, conflict-free), part[4][1024] double-flush.
__launch_bounds__(256, 4)
__global__ void hmlp_kernel(const float* __restrict__ Tg, const ushort_t* __restrict__ Sb,
                            const float* __restrict__ Wg, const uint_t* __restrict__ pbw,
                            const float* __restrict__ b_out_p, float* __restrict__ Og) {
  __shared__ float part[4][1024];      // 16 KB: half-row partials (flushed 2x)
  __shared__ ushort_t Bst[2][4096];    // 16 KB: double-buffered 8KB B tile
  const int tid  = threadIdx.x;
  const int lane = tid & 63;
  const int wv   = tid >> 6;
  const int half = lane >> 5;     // lane half (0/1)
  const int l5   = lane & 31;
  const int blk  = blockIdx.x;
  const int b    = blk >> 11;     // 2048 blocks per batch
  const int i    = blk & 2047;
  const int hb   = wv << 5;       // this wave's h-base (0/32/64/96)

  // one-time unpack: bias' -> MFMA C-in seed, w' -> packed float2 pairs
  // h_r = hb + (r&3) + 8*(r>>2) + 4*half  (C/D row map, verified)
  f32x16 cinit;
  f32x2 w2[8];
#pragma unroll
  for (int r = 0; r < 16; ++r) {
    uint_t pw = pbw[hb + (r & 3) + 8 * (r >> 2) + 4 * half];
    cinit[r] = bflo(pw);
    if (r & 1) w2[r >> 1].y = bfhi(pw); else w2[r >> 1].x = bfhi(pw);
  }

  // ---- A-fragments afr[ks] = bf16(LOG2E * t_i[d] * W[h][d]) ----
  // A row = hb + l5, k(=d) = ks*16 + half*8 + e   (verified)
  bf16x8 afr[8];
  {
    const float* tb = Tg + ((size_t)(b * NN + i)) * DIM;
    const float* wr = Wg + (size_t)(hb + l5) * DIM;
#pragma unroll
    for (int ks = 0; ks < 8; ++ks) {
      const int d0 = ks * 16 + half * 8;
      float4 w0 = *reinterpret_cast<const float4*>(wr + d0);
      float4 w1 = *reinterpret_cast<const float4*>(wr + d0 + 4);
      float4 t0 = *reinterpret_cast<const float4*>(tb + d0);
      float4 t1 = *reinterpret_cast<const float4*>(tb + d0 + 4);
      ushort8 u;
      u[0] = f2bf(w0.x * t0.x * LOG2E); u[1] = f2bf(w0.y * t0.y * LOG2E);
      u[2] = f2bf(w0.z * t0.z * LOG2E); u[3] = f2bf(w0.w * t0.w * LOG2E);
      u[4] = f2bf(w1.x * t1.x * LOG2E); u[5] = f2bf(w1.y * t1.y * LOG2E);
      u[6] = f2bf(w1.z * t1.z * LOG2E); u[7] = f2bf(w1.w * t1.w * LOG2E);
      afr[ks] = __builtin_bit_cast(bf16x8, u);
    }
  }

  // ---- B staging: async global->LDS, 16B/lane, 2 instrs per wave per jt ----
  const ushort_t* stage_base = Sb + (size_t)b * (64 * 4096);

  auto stage_async = [&](int jt, int buf) {
    const ushort_t* g0 = stage_base + (size_t)jt * 4096 + wv * 1024 + lane * 8;
    ushort_t* l0 = &Bst[buf][wv * 1024];
    __builtin_amdgcn_global_load_lds(
        (const __attribute__((address_space(1))) uint_t*)(g0),
        (__attribute__((address_space(3))) uint_t*)(l0), 16, 0, 0);
    __builtin_amdgcn_global_load_lds(
        (const __attribute__((address_space(1))) uint_t*)(g0 + 512),
        (__attribute__((address_space(3))) uint_t*)(l0 + 512), 16, 0, 0);
  };

  // single 8-deep MFMA chain from LDS buffer `buf`, seeded with bias (cinit)
  auto chain = [&](int buf) -> f32x16 {
    const ushort_t* fb = &Bst[buf][lane * 8];
    f32x16 c = __builtin_amdgcn_mfma_f32_32x32x16_bf16(
        afr[0], *reinterpret_cast<const bf16x8*>(fb), cinit, 0, 0, 0);
#pragma unroll
    for (int ks = 1; ks < 8; ++ks)
      c = __builtin_amdgcn_mfma_f32_32x32x16_bf16(
          afr[ks], *reinterpret_cast<const bf16x8*>(fb + ks * 512), c, 0, 0, 0);
    return c;
  };

  // epilogue for accumulator `c` belonging to j-tile `jtv`
  // per pair: 2 exp2 + 1 pk_add + 2 rcp + 1 pk_mul + 1 pk_fma  (7 slots)
  auto epi = [&](const f32x16& c, int jtv) {
    f32x2 pc[2] = {f32x2{0.f, 0.f}, f32x2{0.f, 0.f}};
#define EPI_Q(q)                                                                     \
    {                                                                                \
      f32x2 y = __builtin_shufflevector(c, c, 2 * (q), 2 * (q) + 1);                 \
      float e0 = __builtin_amdgcn_exp2f(-y.x);                                       \
      float e1 = __builtin_amdgcn_exp2f(-y.y);                                       \
      f32x2 d = f32x2{e0, e1} + 1.0f;                                                \
      f32x2 s = f32x2{__builtin_amdgcn_rcpf(d.x), __builtin_amdgcn_rcpf(d.y)};       \
      f32x2 ys = y * s;                                                              \
      pc[(q) & 1] = __builtin_elementwise_fma(w2[(q)], ys, pc[(q) & 1]);             \
    }
    EPI_Q(0) EPI_Q(1) EPI_Q(2) EPI_Q(3) EPI_Q(4) EPI_Q(5) EPI_Q(6) EPI_Q(7)
#undef EPI_Q
    f32x2 pv = pc[0] + pc[1];
    float p = pv.x + pv.y;
    p += __shfl_xor(p, 32, 64);                        // combine lane-halves' h-subsets
    if (lane < 32) part[wv][(jtv & 31) * 32 + l5] = p; // write-once, private row
  };

  const float bo = b_out_p[0];
  const size_t ob = ((size_t)(b * NN + i)) * MM;

  auto flush = [&](int phase) {
    const int j0 = tid * 4;
    f32x4 v0 = *reinterpret_cast<const f32x4*>(&part[0][j0]);
    f32x4 v1 = *reinterpret_cast<const f32x4*>(&part[1][j0]);
    f32x4 v2 = *reinterpret_cast<const f32x4*>(&part[2][j0]);
    f32x4 v3 = *reinterpret_cast<const f32x4*>(&part[3][j0]);
    f32x4 o = (v0 + v1) + (v2 + v3);
    o[0] += bo; o[1] += bo; o[2] += bo; o[3] += bo;
    *reinterpret_cast<f32x4*>(&Og[ob + phase * 1024 + j0]) = o;
  };

  // ---- prologue: stage jt=0 and jt=1; compute cA = chain(jt=0) ----
  stage_async(0, 0);
  __syncthreads();                 // jt0 staged
  stage_async(1, 1);
  f32x16 cA = chain(0);            // jt = 0
  f32x16 cB;
  __syncthreads();                 // jt1 staged; all reads of Bst[0] done

  // ---- pipelined loop: MFMA(jt) || epilogue(jt-1), unrolled x2 ----
#pragma unroll 1
  for (int jt = 1; jt < 63; jt += 2) {
    // iter A: jt (odd, buf 1); epilogue for jt-1 (cA)
    stage_async(jt + 1, 0);
    cB = chain(1);
    epi(cA, jt - 1);               // (jt-1)&31 never 31 here (even)
    __syncthreads();               // stage(jt+1) landed; Bst[1] reads done

    // iter B: jt+1 (even, buf 0); epilogue for jt (cB)
    if (jt + 2 < 64) stage_async(jt + 2, 1);
    cA = chain(0);
    epi(cB, jt);
    __syncthreads();               // stage(jt+2) landed; Bst[0] reads done
    if ((jt & 31) == 31) {         // jt==31: phase-0 rows complete
      flush(0);
      __syncthreads();             // flush reads done before rows reused
    }
  }

  // ---- tail: jt=63 (buf 1, staged at jt=61 iterB) ----
  cB = chain(1);
  epi(cA, 62);
  epi(cB, 63);
  __syncthreads();                 // all phase-1 rows written
  flush(1);
}

// ---------------- launch ----------------
extern "C" void kernel_launch(void* const* d_in, const int* in_sizes, int n_in,
                              void* d_out, int out_size, void* d_ws, size_t ws_size,
                              hipStream_t stream) {
  const float* Tg    = (const float*)d_in[0];
  const float* Sg    = (const float*)d_in[1];
  const float* Wg    = (const float*)d_in[2];
  const float* b_in  = (const float*)d_in[3];
  const float* W_out = (const float*)d_in[4];
  const float* b_out = (const float*)d_in[5];
  float* Og = (float*)d_out;

  ushort_t* Sb = (ushort_t*)d_ws;
  uint_t* pbw  = (uint_t*)((char*)d_ws + (size_t)BATCH * MM * DIM * 2);

  cvt_repack<<<(BATCH * MM * DIM) / (256 * 8), 256, 0, stream>>>(Sg, Sb);
  pbw_kernel<<<1, 128, 0, stream>>>(b_in, W_out, pbw);
  hmlp_kernel<<<BATCH * NN, 256, 0, stream>>>(Tg, Sb, Wg, pbw, b_out, Og);
}

// Round 21
// 699.385 us; speedup vs baseline: 1.1918x; 1.0007x over previous
//
#include <hip/hip_runtime.h>

#define BATCH 4
#define NN 2048
#define MM 2048
#define DIM 128
#define HID 128

typedef __bf16 bf16x8 __attribute__((ext_vector_type(8)));
typedef float f32x16 __attribute__((ext_vector_type(16)));
typedef float f32x4 __attribute__((ext_vector_type(4)));
typedef float f32x2 __attribute__((ext_vector_type(2)));
typedef unsigned short ushort_t;
typedef ushort_t ushort8 __attribute__((ext_vector_type(8)));
typedef unsigned int uint_t;

#define LOG2E 1.44269504088896340736f
#define LN2   0.69314718055994530942f

__device__ __forceinline__ ushort_t f2bf(float f) {
  uint_t u = __builtin_bit_cast(uint_t, f);
  u += 0x7fffu + ((u >> 16) & 1u);
  return (ushort_t)(u >> 16);
}
__device__ __forceinline__ float bflo(uint_t p) { return __builtin_bit_cast(float, p << 16); }
__device__ __forceinline__ float bfhi(uint_t p) { return __builtin_bit_cast(float, p & 0xffff0000u); }

// ---- pre-kernel: fp32 -> bf16 convert + TILE-MAJOR repack of source_val ----
// Lane-linear layout (round-6 verified): chunk t = ((b*64 + jt)*8 + ks)*64 + c
// with c == consuming LANE: half = c>>5, l5 = c&31; chunk holds
// S[b][jt*32+l5][ks*16+half*8 .. +8] as 8 bf16. Per-(jt,ks) fragment read is
// lane*16B linear -> conflict-free ds_read_b128; matches global_load_lds's
// uniform-base+lane*16 dest requirement.
__global__ void cvt_repack(const float* __restrict__ src, ushort_t* __restrict__ dst) {
  int t = blockIdx.x * 256 + threadIdx.x;   // 131072 chunks
  int c    = t & 63;
  int ks   = (t >> 6) & 7;
  int jt   = (t >> 9) & 63;
  int b    = t >> 15;
  int half = c >> 5, l5 = c & 31;           // lane-linear: c == lane
  int j    = jt * 32 + l5;
  int d0   = ks * 16 + half * 8;
  const float* s = src + ((size_t)(b * MM + j)) * DIM + d0;
  float4 v0 = *reinterpret_cast<const float4*>(s);
  float4 v1 = *reinterpret_cast<const float4*>(s + 4);
  ushort8 u;
  u[0] = f2bf(v0.x); u[1] = f2bf(v0.y); u[2] = f2bf(v0.z); u[3] = f2bf(v0.w);
  u[4] = f2bf(v1.x); u[5] = f2bf(v1.y); u[6] = f2bf(v1.z); u[7] = f2bf(v1.w);
  *reinterpret_cast<ushort8*>(dst + (size_t)t * 8) = u;
}

// ---- pre-kernel: pack (b_in*log2e, w_out*ln2) as bf16 pair per h ----
__global__ void pbw_kernel(const float* __restrict__ b_in, const float* __restrict__ w_out,
                           uint_t* __restrict__ pbw) {
  int h = threadIdx.x;
  pbw[h] = (uint_t)f2bf(b_in[h] * LOG2E) | ((uint_t)f2bf(w_out[h] * LN2) << 16);
}

// ---------------- main kernel ----------------
// FINAL (r16 state, verified 699.86us PASS): 8192 blocks = one (b,i); 4 waves;
// wave wv owns h-quarter [32wv,32wv+32).
// Structure (each piece A/B-verified over the session):
//   * deferred-epilogue software pipeline: MFMA(jt) co-scheduled with
//     epilogue(jt-1) via carried cA/cB accumulators (unroll x2, named regs)
//     -- fills the trans pipe from the MFMA/lgkm shadow (r15: killed spill,
//     VALUBusy 59->69%).
//   * (256,4): 4 blocks/CU residency; live set fits the 128-reg combined
//     VGPR+AGPR budget (WRITE == 65536 KB exactly -- no scratch).
//   * cinit bias-fold into MFMA C-in + f32 w2[] pairs: lean 7-slot/pair
//     epilogue (r16: -30us vs unpack-in-loop).
//   * global_load_lds width-16 staged B double-buffer, lane-linear tile-major
//     repack: conflict-free ds_read_b128, zero staging VGPRs (r7).
//   * part[4][1024] write-once rows, double-flush (r11).
// Known floor: VALUBusy 69% == trans-pipe (2 exp2 + 2 rcp per pair @ 16
// cyc/wave-instr = 437us) + pk ops. rcp-elimination via Newton failed
// correctness 4x (re-poisoned data exercises v_rcp's exactness at d = 2^k;
// Newton's ~6.5e-6 residual x |ref|~9e8 = absmax 5888). v_rcp stays.
__launch_bounds__(256, 4)
__global__ void hmlp_kernel(const float* __restrict__ Tg, const ushort_t* __restrict__ Sb,
                            const float* __restrict__ Wg, const uint_t* __restrict__ pbw,
                            const float* __restrict__ b_out_p, float* __restrict__ Og) {
  __shared__ float part[4][1024];      // 16 KB: half-row partials (flushed 2x)
  __shared__ ushort_t Bst[2][4096];    // 16 KB: double-buffered 8KB B tile
  const int tid  = threadIdx.x;
  const int lane = tid & 63;
  const int wv   = tid >> 6;
  const int half = lane >> 5;     // lane half (0/1)
  const int l5   = lane & 31;
  const int blk  = blockIdx.x;
  const int b    = blk >> 11;     // 2048 blocks per batch
  const int i    = blk & 2047;
  const int hb   = wv << 5;       // this wave's h-base (0/32/64/96)

  // one-time unpack: bias' -> MFMA C-in seed, w' -> packed float2 pairs
  // h_r = hb + (r&3) + 8*(r>>2) + 4*half  (C/D row map, verified)
  f32x16 cinit;
  f32x2 w2[8];
#pragma unroll
  for (int r = 0; r < 16; ++r) {
    uint_t pw = pbw[hb + (r & 3) + 8 * (r >> 2) + 4 * half];
    cinit[r] = bflo(pw);
    if (r & 1) w2[r >> 1].y = bfhi(pw); else w2[r >> 1].x = bfhi(pw);
  }

  // ---- A-fragments afr[ks] = bf16(LOG2E * t_i[d] * W[h][d]) ----
  // A row = hb + l5, k(=d) = ks*16 + half*8 + e   (verified)
  bf16x8 afr[8];
  {
    const float* tb = Tg + ((size_t)(b * NN + i)) * DIM;
    const float* wr = Wg + (size_t)(hb + l5) * DIM;
#pragma unroll
    for (int ks = 0; ks < 8; ++ks) {
      const int d0 = ks * 16 + half * 8;
      float4 w0 = *reinterpret_cast<const float4*>(wr + d0);
      float4 w1 = *reinterpret_cast<const float4*>(wr + d0 + 4);
      float4 t0 = *reinterpret_cast<const float4*>(tb + d0);
      float4 t1 = *reinterpret_cast<const float4*>(tb + d0 + 4);
      ushort8 u;
      u[0] = f2bf(w0.x * t0.x * LOG2E); u[1] = f2bf(w0.y * t0.y * LOG2E);
      u[2] = f2bf(w0.z * t0.z * LOG2E); u[3] = f2bf(w0.w * t0.w * LOG2E);
      u[4] = f2bf(w1.x * t1.x * LOG2E); u[5] = f2bf(w1.y * t1.y * LOG2E);
      u[6] = f2bf(w1.z * t1.z * LOG2E); u[7] = f2bf(w1.w * t1.w * LOG2E);
      afr[ks] = __builtin_bit_cast(bf16x8, u);
    }
  }

  // ---- B staging: async global->LDS, 16B/lane, 2 instrs per wave per jt ----
  const ushort_t* stage_base = Sb + (size_t)b * (64 * 4096);

  auto stage_async = [&](int jt, int buf) {
    const ushort_t* g0 = stage_base + (size_t)jt * 4096 + wv * 1024 + lane * 8;
    ushort_t* l0 = &Bst[buf][wv * 1024];
    __builtin_amdgcn_global_load_lds(
        (const __attribute__((address_space(1))) uint_t*)(g0),
        (__attribute__((address_space(3))) uint_t*)(l0), 16, 0, 0);
    __builtin_amdgcn_global_load_lds(
        (const __attribute__((address_space(1))) uint_t*)(g0 + 512),
        (__attribute__((address_space(3))) uint_t*)(l0 + 512), 16, 0, 0);
  };

  // single 8-deep MFMA chain from LDS buffer `buf`, seeded with bias (cinit)
  auto chain = [&](int buf) -> f32x16 {
    const ushort_t* fb = &Bst[buf][lane * 8];
    f32x16 c = __builtin_amdgcn_mfma_f32_32x32x16_bf16(
        afr[0], *reinterpret_cast<const bf16x8*>(fb), cinit, 0, 0, 0);
#pragma unroll
    for (int ks = 1; ks < 8; ++ks)
      c = __builtin_amdgcn_mfma_f32_32x32x16_bf16(
          afr[ks], *reinterpret_cast<const bf16x8*>(fb + ks * 512), c, 0, 0, 0);
    return c;
  };

  // epilogue for accumulator `c` belonging to j-tile `jtv`
  // per pair: 2 exp2 + 1 pk_add + 2 rcp + 1 pk_mul + 1 pk_fma  (7 slots)
  auto epi = [&](const f32x16& c, int jtv) {
    f32x2 pc[2] = {f32x2{0.f, 0.f}, f32x2{0.f, 0.f}};
#define EPI_Q(q)                                                                     \
    {                                                                                \
      f32x2 y = __builtin_shufflevector(c, c, 2 * (q), 2 * (q) + 1);                 \
      float e0 = __builtin_amdgcn_exp2f(-y.x);                                       \
      float e1 = __builtin_amdgcn_exp2f(-y.y);                                       \
      f32x2 d = f32x2{e0, e1} + 1.0f;                                                \
      f32x2 s = f32x2{__builtin_amdgcn_rcpf(d.x), __builtin_amdgcn_rcpf(d.y)};       \
      f32x2 ys = y * s;                                                              \
      pc[(q) & 1] = __builtin_elementwise_fma(w2[(q)], ys, pc[(q) & 1]);             \
    }
    EPI_Q(0) EPI_Q(1) EPI_Q(2) EPI_Q(3) EPI_Q(4) EPI_Q(5) EPI_Q(6) EPI_Q(7)
#undef EPI_Q
    f32x2 pv = pc[0] + pc[1];
    float p = pv.x + pv.y;
    p += __shfl_xor(p, 32, 64);                        // combine lane-halves' h-subsets
    if (lane < 32) part[wv][(jtv & 31) * 32 + l5] = p; // write-once, private row
  };

  const float bo = b_out_p[0];
  const size_t ob = ((size_t)(b * NN + i)) * MM;

  auto flush = [&](int phase) {
    const int j0 = tid * 4;
    f32x4 v0 = *reinterpret_cast<const f32x4*>(&part[0][j0]);
    f32x4 v1 = *reinterpret_cast<const f32x4*>(&part[1][j0]);
    f32x4 v2 = *reinterpret_cast<const f32x4*>(&part[2][j0]);
    f32x4 v3 = *reinterpret_cast<const f32x4*>(&part[3][j0]);
    f32x4 o = (v0 + v1) + (v2 + v3);
    o[0] += bo; o[1] += bo; o[2] += bo; o[3] += bo;
    *reinterpret_cast<f32x4*>(&Og[ob + phase * 1024 + j0]) = o;
  };

  // ---- prologue: stage jt=0 and jt=1; compute cA = chain(jt=0) ----
  stage_async(0, 0);
  __syncthreads();                 // jt0 staged
  stage_async(1, 1);
  f32x16 cA = chain(0);            // jt = 0
  f32x16 cB;
  __syncthreads();                 // jt1 staged; all reads of Bst[0] done

  // ---- pipelined loop: MFMA(jt) || epilogue(jt-1), unrolled x2 ----
#pragma unroll 1
  for (int jt = 1; jt < 63; jt += 2) {
    // iter A: jt (odd, buf 1); epilogue for jt-1 (cA)
    stage_async(jt + 1, 0);
    cB = chain(1);
    epi(cA, jt - 1);               // (jt-1)&31 never 31 here (even)
    __syncthreads();               // stage(jt+1) landed; Bst[1] reads done

    // iter B: jt+1 (even, buf 0); epilogue for jt (cB)
    if (jt + 2 < 64) stage_async(jt + 2, 1);
    cA = chain(0);
    epi(cB, jt);
    __syncthreads();               // stage(jt+2) landed; Bst[0] reads done
    if ((jt & 31) == 31) {         // jt==31: phase-0 rows complete
      flush(0);
      __syncthreads();             // flush reads done before rows reused
    }
  }

  // ---- tail: jt=63 (buf 1, staged at jt=61 iterB) ----
  cB = chain(1);
  epi(cA, 62);
  epi(cB, 63);
  __syncthreads();                 // all phase-1 rows written
  flush(1);
}

// ---------------- launch ----------------
extern "C" void kernel_launch(void* const* d_in, const int* in_sizes, int n_in,
                              void* d_out, int out_size, void* d_ws, size_t ws_size,
                              hipStream_t stream) {
  const float* Tg    = (const float*)d_in[0];
  const float* Sg    = (const float*)d_in[1];
  const float* Wg    = (const float*)d_in[2];
  const float* b_in  = (const float*)d_in[3];
  const float* W_out = (const float*)d_in[4];
  const float* b_out = (const float*)d_in[5];
  float* Og = (float*)d_out;

  ushort_t* Sb = (ushort_t*)d_ws;
  uint_t* pbw  = (uint_t*)((char*)d_ws + (size_t)BATCH * MM * DIM * 2);

  cvt_repack<<<(BATCH * MM * DIM) / (256 * 8), 256, 0, stream>>>(Sg, Sb);
  pbw_kernel<<<1, 128, 0, stream>>>(b_in, W_out, pbw);
  hmlp_kernel<<<BATCH * NN, 256, 0, stream>>>(Tg, Sb, Wg, pbw, b_out, Og);
}